// Round 2
// baseline (1648.306 us; speedup 1.0000x reference)
//
#include <hip/hip_runtime.h>
#include <stdint.h>

// ---------------- problem constants ----------------
#define NTOK   16384      // B*T
#define DMODEL 1024
#define HID    4096
#define NE     8
#define TOPK   2
#define CAP    2458       // ceil(1.2*16384/8)
#define CAPP   2560       // CAP padded to 256 multiple (10 tiles of 256)
#define MASS   32768      // NTOK*TOPK
#define NBUCKET 16384     // max assignments per expert

typedef __attribute__((ext_vector_type(8))) unsigned short us8;
typedef __attribute__((ext_vector_type(8))) _Float16 half8;
typedef __attribute__((ext_vector_type(4))) float float4v;

__device__ __forceinline__ unsigned short f2h_bits(float f) {
    _Float16 h = (_Float16)f;
    union { _Float16 h; unsigned short u; } cv; cv.h = h; return cv.u;
}

// async global->LDS 16B. LDS dest must be wave-uniform base + lane*16,
// which our chunk-major staging layout guarantees (lane-linear per wave).
typedef const __attribute__((address_space(1))) unsigned int ga_u32;
typedef __attribute__((address_space(3))) unsigned int lds_u32;
__device__ __forceinline__ void gl2lds16(const void* g, void* l) {
    __builtin_amdgcn_global_load_lds((ga_u32*)g, (lds_u32*)l, 16, 0, 0);
}

// ---------------- router: logits -> softmax -> top2 (f64 for ranking safety) ----------------
__global__ __launch_bounds__(256)
void router_kernel(const float* __restrict__ x,
                   const float* __restrict__ Wr,
                   const float* __restrict__ br,
                   int* __restrict__ aexp, float* __restrict__ agate)
{
    __shared__ float WrT[8 * 1025];
    const int t = threadIdx.x;
    for (int idx = t; idx < DMODEL * NE; idx += 256) {
        int d = idx >> 3, e = idx & 7;
        WrT[e * 1025 + d] = Wr[idx];
    }
    __syncthreads();
    const int w = t >> 6, lane = t & 63;
    const int n = blockIdx.x * 4 + w;
    double acc[NE];
#pragma unroll
    for (int e = 0; e < NE; ++e) acc[e] = 0.0;
    const float* xr = x + (long long)n * DMODEL;
#pragma unroll 4
    for (int i = 0; i < 16; ++i) {
        int d = i * 64 + lane;
        double xv = (double)xr[d];
#pragma unroll
        for (int e = 0; e < NE; ++e) acc[e] += xv * (double)WrT[e * 1025 + d];
    }
#pragma unroll
    for (int e = 0; e < NE; ++e) {
#pragma unroll
        for (int off = 1; off < 64; off <<= 1)
            acc[e] += __shfl_xor(acc[e], off, 64);
        acc[e] += (double)br[e];
    }
    double mx = acc[0];
#pragma unroll
    for (int e = 1; e < NE; ++e) mx = acc[e] > mx ? acc[e] : mx;
    double p[NE], s = 0.0;
#pragma unroll
    for (int e = 0; e < NE; ++e) { p[e] = exp(acc[e] - mx); s += p[e]; }
    double inv = 1.0 / s;
#pragma unroll
    for (int e = 0; e < NE; ++e) p[e] *= inv;
    // top-2 with lowest-index tie-break (matches lax.top_k)
    int id0 = 0; double g0 = p[0];
#pragma unroll
    for (int e = 1; e < NE; ++e) if (p[e] > g0) { g0 = p[e]; id0 = e; }
    int id1 = -1; double g1 = -1.0;
#pragma unroll
    for (int e = 0; e < NE; ++e) if (e != id0 && p[e] > g1) { g1 = p[e]; id1 = e; }
    if (lane == 0) {
        aexp[2 * n] = id0;     agate[2 * n] = (float)g0;
        aexp[2 * n + 1] = id1; agate[2 * n + 1] = (float)g1;
    }
}

// ---------------- bucket assignments per expert ----------------
__global__ __launch_bounds__(256)
void bucket_kernel(const int* __restrict__ aexp, const float* __restrict__ agate,
                   int* __restrict__ cnt, float* __restrict__ bg, int* __restrict__ bm)
{
    int m = blockIdx.x * 256 + threadIdx.x;
    if (m >= MASS) return;
    int e = aexp[m];
    int i = atomicAdd(&cnt[e], 1);
    bg[e * NBUCKET + i] = agate[m];
    bm[e * NBUCKET + i] = m;
}

// ---------------- exact rank within expert (gate desc, flat-idx asc); build dispatch ----------------
__global__ __launch_bounds__(256)
void rank_kernel(const int* __restrict__ cnt,
                 const float* __restrict__ bg, const int* __restrict__ bm,
                 int* __restrict__ disp_tok, float* __restrict__ disp_g)
{
    const int e = blockIdx.y;
    const int n = cnt[e];
    if ((int)blockIdx.x * 256 >= n) return;
    const int t = threadIdx.x;
    const int i = blockIdx.x * 256 + t;
    const bool active = i < n;
    const float* bge = bg + e * NBUCKET;
    const int* bme = bm + e * NBUCKET;
    float gi = active ? bge[i] : -1.f;
    int   mi = active ? bme[i] : 0x7fffffff;
    __shared__ float sg[256];
    __shared__ int   sm[256];
    int rank = 0;
    for (int j0 = 0; j0 < n; j0 += 256) {
        int j = j0 + t;
        if (j < n) { sg[t] = bge[j]; sm[t] = bme[j]; }
        __syncthreads();
        int lim = n - j0; if (lim > 256) lim = 256;
#pragma unroll 8
        for (int jj = 0; jj < lim; ++jj) {
            float gj = sg[jj]; int mj = sm[jj];
            rank += (gj > gi || (gj == gi && mj < mi)) ? 1 : 0;
        }
        __syncthreads();
    }
    if (active && rank < CAP) {
        int slot = e * CAP + rank;
        disp_tok[slot] = mi >> 1;   // token index
        disp_g[slot] = gi;
    }
}

// ---------------- f32 -> f16 convert (x) ----------------
__global__ __launch_bounds__(256)
void cvt_kernel(const float* __restrict__ in, unsigned short* __restrict__ out)
{
    int i = (blockIdx.x * 256 + threadIdx.x) * 8;
    float4v a = *(const float4v*)&in[i];
    float4v b = *(const float4v*)&in[i + 4];
    us8 o;
#pragma unroll
    for (int j = 0; j < 4; ++j) { o[j] = f2h_bits(a[j]); o[4 + j] = f2h_bits(b[j]); }
    *(us8*)&out[i] = o;
}

// ---------------- transpose + f32->f16: src [R][C] -> dst [C][R] ----------------
__global__ __launch_bounds__(256)
void transpose_kernel(const float* __restrict__ src, long long src_es,
                      unsigned short* __restrict__ dst, long long dst_es,
                      int R, int C)
{
    __shared__ unsigned short tile[64 * 72];
    const int t = threadIdx.x;
    const int c0 = blockIdx.x * 64, r0 = blockIdx.y * 64;
    const float* S = src + (long long)blockIdx.z * src_es;
    unsigned short* D = dst + (long long)blockIdx.z * dst_es;
#pragma unroll
    for (int i = 0; i < 2; ++i) {
        int chunk = i * 256 + t;           // 0..511, 8 elems each
        int tr = chunk >> 3, tc = (chunk & 7) * 8;
        const float* sp = &S[(long long)(r0 + tr) * C + c0 + tc];
        float4v a = *(const float4v*)sp;
        float4v b = *(const float4v*)(sp + 4);
        us8 o;
#pragma unroll
        for (int j = 0; j < 4; ++j) { o[j] = f2h_bits(a[j]); o[4 + j] = f2h_bits(b[j]); }
        *(us8*)&tile[tr * 72 + tc] = o;
    }
    __syncthreads();
#pragma unroll
    for (int i = 0; i < 2; ++i) {
        int chunk = i * 256 + t;
        int wc = chunk & 63;
        int r8 = (chunk >> 6) * 8;
        us8 v;
#pragma unroll
        for (int j = 0; j < 8; ++j) v[j] = tile[(r8 + j) * 72 + wc];
        *(us8*)&D[(long long)(c0 + wc) * R + r0 + r8] = v;
    }
}

// ---------------- 256x256 2-phase pipelined GEMM ----------------
// C[M x N] = A[M x K] * Bt[N x K]^T, f16 in, f32 MFMA accum.
// BM=BN=256, BK=64, 512 threads = 8 waves (2 M-groups x 4 N-groups),
// per-wave output 128x64 (MI=8, NI=4 fragments of 16x16).
// LDS: 2 dbuf x (A 32KB + B 32KB) = 128 KiB, chunk-major [c8][256 rows][8 f16]
// so global_load_lds dests are lane-linear and ds_read_b128 frags contiguous.
// 2-phase K-loop (T3-minimum, regime-gated to 256² per m230/m248):
//   STAGE(next) issued BEFORE COMPUTE(cur); one __syncthreads per K-step.
// XCD-chunked bijective swizzle (kept from r1: FETCH 746->230 MB).
// kSplit: split-K for GEMM2 (N=1024): piece p covers K-range [p*K/kSplit, ...),
// only piece 0 adds bias (output is atomic f32 accumulate).
template<bool GATHER, bool SILU_F16, bool ATOMIC_OUT>
__global__ __launch_bounds__(512, 2)
void gemm_pipe(const unsigned short* __restrict__ A, long long A_es,
               const unsigned short* __restrict__ Bt, long long Bt_es,
               void* __restrict__ Out, long long Out_es,
               const float* __restrict__ bias, long long bias_es,
               const int* __restrict__ rowmap, long long rowmap_es,
               const float* __restrict__ gate, long long gate_es,
               int K, int N, int Mvalid, int kSplit)
{
    // --- XCD-chunked swizzle (bijective: all our grids have nwg%8==0, gx%4==0... gx>=4) ---
    const int gx = gridDim.x, gy = gridDim.y;
    int bx = blockIdx.x, by = blockIdx.y, bz = blockIdx.z;
    {
        const int nwg = gx * gy * (int)gridDim.z;
        if ((nwg & 7) == 0 && (gx & 3) == 0) {
            int lin = (bz * gy + by) * gx + bx;
            int o = (lin & 7) * (nwg >> 3) + (lin >> 3);   // XCD (lin%8) gets contiguous chunk
            const int pe = gx * gy;                        // tiles per z-slice
            bz = o / pe;
            int r = o % pe;                                // within slice: 4-col groups, y fast
            const int gsz = 4 * gy;
            int xg = r / gsz, r2 = r % gsz;
            by = r2 >> 2;
            bx = xg * 4 + (r2 & 3);
        }
    }
    const int e = bz / kSplit;              // expert
    const int piece = bz - e * kSplit;      // split-K piece
    const int kLen = K / kSplit;
    const int kStart = piece * kLen;

    const int t = threadIdx.x;
    const int n0 = bx * 256;
    const int r0 = by * 256;

    __shared__ alignas(16) unsigned short sA[2][16384];   // [c8][256][8] x 2 buf
    __shared__ alignas(16) unsigned short sB[2][16384];

    const int rs = t & 255;
    const int hA = t >> 8;                  // 0..1
    const unsigned short* aRow;
    if (GATHER) {
        const int* rm = rowmap + (size_t)e * rowmap_es;
        int rr = r0 + rs; if (rr >= Mvalid) rr = Mvalid - 1;
        int tok = rm[rr];
        aRow = A + (long long)tok * K;
    } else {
        aRow = A + (long long)e * A_es + (long long)(r0 + rs) * K;
    }
    const unsigned short* bRow = Bt + (long long)e * Bt_es + (long long)(n0 + rs) * K;

    const int lane = t & 63;
    const int w = t >> 6;                   // 0..7
    const int wy = w >> 2, wx = w & 3;      // 2 M-groups x 4 N-groups
    const int lm = lane & 15, lq = lane >> 4;

    float4v acc[8][4];
#pragma unroll
    for (int a = 0; a < 8; ++a)
#pragma unroll
        for (int b = 0; b < 4; ++b) acc[a][b] = (float4v){0.f, 0.f, 0.f, 0.f};

    auto STAGE = [&](int buf, int kb) {
        const int kOff = kStart + (kb << 6);
#pragma unroll
        for (int i = 0; i < 4; ++i) {
            const int c8 = i * 2 + hA;
            gl2lds16(aRow + kOff + c8 * 8, &sA[buf][(c8 * 256 + rs) * 8]);
            gl2lds16(bRow + kOff + c8 * 8, &sB[buf][(c8 * 256 + rs) * 8]);
        }
    };
    auto COMPUTE = [&](int buf) {
#pragma unroll
        for (int ks = 0; ks < 2; ++ks) {
            const int c8k = ks * 4 + lq;
            half8 af[8], bf[4];
#pragma unroll
            for (int mi = 0; mi < 8; ++mi) {
                int m = wy * 128 + mi * 16 + lm;
                af[mi] = *(const half8*)&sA[buf][(c8k * 256 + m) * 8];
            }
#pragma unroll
            for (int ni = 0; ni < 4; ++ni) {
                int nn = wx * 64 + ni * 16 + lm;
                bf[ni] = *(const half8*)&sB[buf][(c8k * 256 + nn) * 8];
            }
#pragma unroll
            for (int mi = 0; mi < 8; ++mi)
#pragma unroll
                for (int ni = 0; ni < 4; ++ni)
                    acc[mi][ni] = __builtin_amdgcn_mfma_f32_16x16x32_f16(
                        af[mi], bf[ni], acc[mi][ni], 0, 0, 0);
        }
    };

    const int KB = kLen >> 6;
    STAGE(0, 0);
    __syncthreads();                        // drains vmcnt(0): buf0 ready
    int cur = 0;
    for (int kb = 0; kb < KB - 1; ++kb) {
        STAGE(cur ^ 1, kb + 1);             // next tile's loads in flight during compute
        COMPUTE(cur);
        __syncthreads();                    // vmcnt(0) drain overlapped by 64 MFMA/wave
        cur ^= 1;
    }
    COMPUTE(cur);

    // epilogue. D mapping: col = lane&15, row = (lane>>4)*4 + reg  [m89-verified]
    const float* biasE = bias + (long long)e * bias_es;
    if (ATOMIC_OUT) {
        float* O = (float*)Out;   // global out [NTOK][N], shared across z
        const int* rm = rowmap + (size_t)e * rowmap_es;
        const float* gE = gate + (size_t)e * gate_es;
        const bool addBias = (piece == 0);
#pragma unroll
        for (int mi = 0; mi < 8; ++mi) {
#pragma unroll
            for (int reg = 0; reg < 4; ++reg) {
                int gr = r0 + wy * 128 + mi * 16 + lq * 4 + reg;
                if (gr >= Mvalid) continue;
                int tok = rm[gr];
                float g = gE[gr];
#pragma unroll
                for (int ni = 0; ni < 4; ++ni) {
                    int gc = n0 + wx * 64 + ni * 16 + lm;
                    float v = (acc[mi][ni][reg] + (addBias ? biasE[gc] : 0.f)) * g;
                    atomicAdd(&O[(long long)tok * N + gc], v);
                }
            }
        }
    } else {
        unsigned short* O = (unsigned short*)Out + (long long)e * Out_es;
#pragma unroll
        for (int mi = 0; mi < 8; ++mi) {
#pragma unroll
            for (int reg = 0; reg < 4; ++reg) {
                int gr = r0 + wy * 128 + mi * 16 + lq * 4 + reg;
#pragma unroll
                for (int ni = 0; ni < 4; ++ni) {
                    int gc = n0 + wx * 64 + ni * 16 + lm;
                    float v = acc[mi][ni][reg] + biasE[gc];
                    if (SILU_F16) v = v / (1.f + __expf(-v));
                    O[(long long)gr * N + gc] = f2h_bits(v);
                }
            }
        }
    }
}

// ---------------- host launcher ----------------
extern "C" void kernel_launch(void* const* d_in, const int* in_sizes, int n_in,
                              void* d_out, int out_size, void* d_ws, size_t ws_size,
                              hipStream_t stream)
{
    if (n_in < 7) return;
    const float* x  = (const float*)d_in[0];
    const float* Wr = (const float*)d_in[1];
    const float* br = (const float*)d_in[2];
    const float* W1 = (const float*)d_in[3];
    const float* b1 = (const float*)d_in[4];
    const float* W2 = (const float*)d_in[5];
    const float* b2 = (const float*)d_in[6];
    float* out = (float*)d_out;
    char* ws = (char*)d_ws;

    // out must start at 0: stage-2 accumulates into it atomically.
    hipMemsetAsync(out, 0, (size_t)out_size * sizeof(float), stream);

    size_t off = 0;
    auto take = [&](size_t sz) { size_t o = off; off += (sz + 255) & ~(size_t)255; return o; };
    const size_t o_aexp  = take(4ull * MASS);
    const size_t o_agate = take(4ull * MASS);
    const size_t o_cnt   = take(256);
    const size_t o_bg    = take(4ull * NE * NBUCKET);
    const size_t o_bm    = take(4ull * NE * NBUCKET);
    const size_t o_dtok  = take(4ull * NE * CAP);
    const size_t o_dg    = take(4ull * NE * CAP);
    const size_t o_xf    = take(2ull * NTOK * DMODEL);
    const size_t misc_end = off;

    // tiers: (fullW,fullH) -> (fullW,slimH) -> (slimW,slimH)
    bool fullW = true, fullH = true;
    size_t o_w1t = 0, o_w2t = 0, o_h = 0;
    bool fits = false;
    for (int attempt = 0; attempt < 3; ++attempt) {
        off = misc_end;
        o_w1t = take((fullW ? (size_t)NE : 1) * 2ull * DMODEL * HID);
        o_w2t = take((fullW ? (size_t)NE : 1) * 2ull * DMODEL * HID);
        o_h   = take((fullH ? (size_t)NE : 1) * 2ull * CAPP * HID);
        if (off <= ws_size) { fits = true; break; }
        if (fullH) fullH = false; else fullW = false;
    }
    if (!fits) return;  // out stays zero -> wrong-answer diagnostic, no OOB crash

    int*   aexp   = (int*)(ws + o_aexp);
    float* agate  = (float*)(ws + o_agate);
    int*   cnt    = (int*)(ws + o_cnt);
    float* bg     = (float*)(ws + o_bg);
    int*   bm     = (int*)(ws + o_bm);
    int*   dtok   = (int*)(ws + o_dtok);
    float* dg     = (float*)(ws + o_dg);
    unsigned short* xf  = (unsigned short*)(ws + o_xf);
    unsigned short* W1T = (unsigned short*)(ws + o_w1t);
    unsigned short* W2T = (unsigned short*)(ws + o_w2t);
    unsigned short* hbuf = (unsigned short*)(ws + o_h);

    hipMemsetAsync(cnt, 0, 256, stream);
    hipMemsetAsync(dtok, 0, 4ull * NE * CAP, stream);   // padded slots -> token 0
    hipMemsetAsync(dg, 0, 4ull * NE * CAP, stream);     // padded slots -> gate 0

    router_kernel<<<NTOK / 4, 256, 0, stream>>>(x, Wr, br, aexp, agate);
    bucket_kernel<<<MASS / 256, 256, 0, stream>>>(aexp, agate, cnt, bg, bm);
    rank_kernel<<<dim3(NBUCKET / 256, NE), 256, 0, stream>>>(cnt, bg, bm, dtok, dg);
    cvt_kernel<<<(NTOK * DMODEL) / (256 * 8), 256, 0, stream>>>(x, xf);

    const long long WS = (long long)DMODEL * HID;
    if (fullW) {
        transpose_kernel<<<dim3(HID / 64, DMODEL / 64, NE), 256, 0, stream>>>(W1, WS, W1T, WS, DMODEL, HID);
        transpose_kernel<<<dim3(DMODEL / 64, HID / 64, NE), 256, 0, stream>>>(W2, WS, W2T, WS, HID, DMODEL);
    }

    if (fullH) {
        // GEMM1: [CAPP x 1024] x [1024 x 4096] per expert
        gemm_pipe<true, true, false><<<dim3(HID / 256, CAPP / 256, NE), 512, 0, stream>>>(
            xf, 0, W1T, WS, hbuf, (long long)CAPP * HID,
            b1, HID, dtok, CAP, (const float*)nullptr, 0, DMODEL, HID, CAP, 1);
        // GEMM2: [CAPP x 4096] x [4096 x 1024] per expert, split-K=2 for grid fill
        gemm_pipe<false, false, true><<<dim3(DMODEL / 256, CAPP / 256, NE * 2), 512, 0, stream>>>(
            hbuf, (long long)CAPP * HID, W2T, WS, out, 0,
            b2, DMODEL, dtok, CAP, dg, CAP, HID, DMODEL, CAP, 2);
    } else {
        for (int e = 0; e < NE; ++e) {
            const unsigned short* w1te;
            const unsigned short* w2te;
            if (fullW) {
                w1te = W1T + (size_t)e * WS;
                w2te = W2T + (size_t)e * WS;
            } else {
                transpose_kernel<<<dim3(HID / 64, DMODEL / 64, 1), 256, 0, stream>>>(
                    W1 + (size_t)e * WS, 0, W1T, 0, DMODEL, HID);
                w1te = W1T; w2te = W2T;
            }
            gemm_pipe<true, true, false><<<dim3(HID / 256, CAPP / 256, 1), 512, 0, stream>>>(
                xf, 0, w1te, 0, hbuf, 0,
                b1 + (size_t)e * HID, 0, dtok + (size_t)e * CAP, 0,
                (const float*)nullptr, 0, DMODEL, HID, CAP, 1);
            if (!fullW)
                transpose_kernel<<<dim3(DMODEL / 64, HID / 64, 1), 256, 0, stream>>>(
                    W2 + (size_t)e * WS, 0, W2T, 0, HID, DMODEL);
            gemm_pipe<false, false, true><<<dim3(DMODEL / 256, CAPP / 256, 2), 512, 0, stream>>>(
                hbuf, 0, w2te, 0, out, 0,
                b2 + (size_t)e * DMODEL, 0, dtok + (size_t)e * CAP, 0,
                dg + (size_t)e * CAP, 0, HID, DMODEL, CAP, 2);
        }
    }
}

// Round 3
// 1093.732 us; speedup vs baseline: 1.5070x; 1.5070x over previous
//
#include <hip/hip_runtime.h>
#include <stdint.h>

// ---------------- problem constants ----------------
#define NTOK   16384      // B*T
#define DMODEL 1024
#define HID    4096
#define NE     8
#define TOPK   2
#define CAP    2458       // ceil(1.2*16384/8)
#define CAPP   2560       // CAP padded to 128 multiple (20 tiles)
#define MASS   32768      // NTOK*TOPK
#define NBUCKET 16384     // max assignments per expert

typedef __attribute__((ext_vector_type(8))) unsigned short us8;
typedef __attribute__((ext_vector_type(8))) _Float16 half8;
typedef __attribute__((ext_vector_type(4))) float float4v;

__device__ __forceinline__ unsigned short f2h_bits(float f) {
    _Float16 h = (_Float16)f;
    union { _Float16 h; unsigned short u; } cv; cv.h = h; return cv.u;
}

// async global->LDS 16B. LDS dest must be wave-uniform base + lane*16.
typedef const __attribute__((address_space(1))) unsigned int ga_u32;
typedef __attribute__((address_space(3))) unsigned int lds_u32;
__device__ __forceinline__ void gl2lds16(const void* g, void* l) {
    __builtin_amdgcn_global_load_lds((ga_u32*)g, (lds_u32*)l, 16, 0, 0);
}

// ---------------- router: logits -> softmax -> top2 (f64 for ranking safety) ----------------
__global__ __launch_bounds__(256)
void router_kernel(const float* __restrict__ x,
                   const float* __restrict__ Wr,
                   const float* __restrict__ br,
                   int* __restrict__ aexp, float* __restrict__ agate)
{
    __shared__ float WrT[8 * 1025];
    const int t = threadIdx.x;
    for (int idx = t; idx < DMODEL * NE; idx += 256) {
        int d = idx >> 3, e = idx & 7;
        WrT[e * 1025 + d] = Wr[idx];
    }
    __syncthreads();
    const int w = t >> 6, lane = t & 63;
    const int n = blockIdx.x * 4 + w;
    double acc[NE];
#pragma unroll
    for (int e = 0; e < NE; ++e) acc[e] = 0.0;
    const float* xr = x + (long long)n * DMODEL;
#pragma unroll 4
    for (int i = 0; i < 16; ++i) {
        int d = i * 64 + lane;
        double xv = (double)xr[d];
#pragma unroll
        for (int e = 0; e < NE; ++e) acc[e] += xv * (double)WrT[e * 1025 + d];
    }
#pragma unroll
    for (int e = 0; e < NE; ++e) {
#pragma unroll
        for (int off = 1; off < 64; off <<= 1)
            acc[e] += __shfl_xor(acc[e], off, 64);
        acc[e] += (double)br[e];
    }
    double mx = acc[0];
#pragma unroll
    for (int e = 1; e < NE; ++e) mx = acc[e] > mx ? acc[e] : mx;
    double p[NE], s = 0.0;
#pragma unroll
    for (int e = 0; e < NE; ++e) { p[e] = exp(acc[e] - mx); s += p[e]; }
    double inv = 1.0 / s;
#pragma unroll
    for (int e = 0; e < NE; ++e) p[e] *= inv;
    // top-2 with lowest-index tie-break (matches lax.top_k)
    int id0 = 0; double g0 = p[0];
#pragma unroll
    for (int e = 1; e < NE; ++e) if (p[e] > g0) { g0 = p[e]; id0 = e; }
    int id1 = -1; double g1 = -1.0;
#pragma unroll
    for (int e = 0; e < NE; ++e) if (e != id0 && p[e] > g1) { g1 = p[e]; id1 = e; }
    if (lane == 0) {
        aexp[2 * n] = id0;     agate[2 * n] = (float)g0;
        aexp[2 * n + 1] = id1; agate[2 * n + 1] = (float)g1;
    }
}

// ---------------- bucket assignments per expert ----------------
__global__ __launch_bounds__(256)
void bucket_kernel(const int* __restrict__ aexp, const float* __restrict__ agate,
                   int* __restrict__ cnt, float* __restrict__ bg, int* __restrict__ bm)
{
    int m = blockIdx.x * 256 + threadIdx.x;
    if (m >= MASS) return;
    int e = aexp[m];
    int i = atomicAdd(&cnt[e], 1);
    bg[e * NBUCKET + i] = agate[m];
    bm[e * NBUCKET + i] = m;
}

// ---------------- exact rank within expert (gate desc, flat-idx asc); build dispatch ----------------
__global__ __launch_bounds__(256)
void rank_kernel(const int* __restrict__ cnt,
                 const float* __restrict__ bg, const int* __restrict__ bm,
                 int* __restrict__ disp_tok, float* __restrict__ disp_g)
{
    const int e = blockIdx.y;
    const int n = cnt[e];
    if ((int)blockIdx.x * 256 >= n) return;
    const int t = threadIdx.x;
    const int i = blockIdx.x * 256 + t;
    const bool active = i < n;
    const float* bge = bg + e * NBUCKET;
    const int* bme = bm + e * NBUCKET;
    float gi = active ? bge[i] : -1.f;
    int   mi = active ? bme[i] : 0x7fffffff;
    __shared__ float sg[256];
    __shared__ int   sm[256];
    int rank = 0;
    for (int j0 = 0; j0 < n; j0 += 256) {
        int j = j0 + t;
        if (j < n) { sg[t] = bge[j]; sm[t] = bme[j]; }
        __syncthreads();
        int lim = n - j0; if (lim > 256) lim = 256;
#pragma unroll 8
        for (int jj = 0; jj < lim; ++jj) {
            float gj = sg[jj]; int mj = sm[jj];
            rank += (gj > gi || (gj == gi && mj < mi)) ? 1 : 0;
        }
        __syncthreads();
    }
    if (active && rank < CAP) {
        int slot = e * CAP + rank;
        disp_tok[slot] = mi >> 1;   // token index
        disp_g[slot] = gi;
    }
}

// ---------------- f32 -> f16 convert (x) ----------------
__global__ __launch_bounds__(256)
void cvt_kernel(const float* __restrict__ in, unsigned short* __restrict__ out)
{
    int i = (blockIdx.x * 256 + threadIdx.x) * 8;
    float4v a = *(const float4v*)&in[i];
    float4v b = *(const float4v*)&in[i + 4];
    us8 o;
#pragma unroll
    for (int j = 0; j < 4; ++j) { o[j] = f2h_bits(a[j]); o[4 + j] = f2h_bits(b[j]); }
    *(us8*)&out[i] = o;
}

// ---------------- transpose + f32->f16: src [R][C] -> dst [C][R] ----------------
__global__ __launch_bounds__(256)
void transpose_kernel(const float* __restrict__ src, long long src_es,
                      unsigned short* __restrict__ dst, long long dst_es,
                      int R, int C)
{
    __shared__ unsigned short tile[64 * 72];
    const int t = threadIdx.x;
    const int c0 = blockIdx.x * 64, r0 = blockIdx.y * 64;
    const float* S = src + (long long)blockIdx.z * src_es;
    unsigned short* D = dst + (long long)blockIdx.z * dst_es;
#pragma unroll
    for (int i = 0; i < 2; ++i) {
        int chunk = i * 256 + t;           // 0..511, 8 elems each
        int tr = chunk >> 3, tc = (chunk & 7) * 8;
        const float* sp = &S[(long long)(r0 + tr) * C + c0 + tc];
        float4v a = *(const float4v*)sp;
        float4v b = *(const float4v*)(sp + 4);
        us8 o;
#pragma unroll
        for (int j = 0; j < 4; ++j) { o[j] = f2h_bits(a[j]); o[4 + j] = f2h_bits(b[j]); }
        *(us8*)&tile[tr * 72 + tc] = o;
    }
    __syncthreads();
#pragma unroll
    for (int i = 0; i < 2; ++i) {
        int chunk = i * 256 + t;
        int wc = chunk & 63;
        int r8 = (chunk >> 6) * 8;
        us8 v;
#pragma unroll
        for (int j = 0; j < 8; ++j) v[j] = tile[(r8 + j) * 72 + wc];
        *(us8*)&D[(long long)(c0 + wc) * R + r0 + r8] = v;
    }
}

// ---------------- 128x128 GEMM, coalesced swizzled staging ----------------
// C[M x N] = A[M x K] * Bt[N x K]^T, f16 in, f32 MFMA accum.
// BM=BN=128, BK=64, 256 thr (2x2 waves), single-buffered LDS (32 KiB ->
// 4-5 blocks/CU, m114 implicit cross-block overlap).
// STAGING FIX (this round): LDS is row-major [128 rows][64 f16] (128 B/row).
// Each row is staged by 8 lanes x 16 B -> every gl2lds16 wave-instruction
// covers 8 CONTIGUOUS 128-B global segments (full cache lines) instead of 64
// scattered 16-B requests (8x fewer L2 transactions; the old pattern was the
// measured ~2cyc/request serial bottleneck, MfmaUtil pinned at ~12%).
// Bank-conflict fix for the row-major reads: XOR swizzle chunk^=(row&7),
// applied BOTH sides (G21): LDS dest stays linear for global_load_lds, the
// GLOBAL source chunk is pre-permuted (stays within the row's 128 B, so
// coalescing is preserved), and the ds_read applies the same XOR.
// Residual conflict: 2-way (lm vs lm+8) = free per m136.
template<bool GATHER, bool SILU_F16, bool ATOMIC_OUT>
__global__ __launch_bounds__(256, 2)
void gemm_bt(const unsigned short* __restrict__ A, long long A_es,
             const unsigned short* __restrict__ Bt, long long Bt_es,
             void* __restrict__ Out, long long Out_es,
             const float* __restrict__ bias, long long bias_es,
             const int* __restrict__ rowmap, long long rowmap_es,
             const float* __restrict__ gate, long long gate_es,
             int K, int N, int Mvalid)
{
    // --- XCD-chunked swizzle (bijective: all our grids have nwg%8==0, gx%4==0) ---
    const int gx = gridDim.x, gy = gridDim.y;
    int bx = blockIdx.x, by = blockIdx.y, bz = blockIdx.z;
    {
        const int nwg = gx * gy * (int)gridDim.z;
        if ((nwg & 7) == 0 && (gx & 3) == 0) {
            int lin = (bz * gy + by) * gx + bx;
            int o = (lin & 7) * (nwg >> 3) + (lin >> 3);   // XCD (lin%8) gets contiguous chunk
            const int pe = gx * gy;                        // tiles per z-slice
            bz = o / pe;
            int r = o % pe;                                // within slice: 4-col groups, y fast
            const int gsz = 4 * gy;
            int xg = r / gsz, r2 = r % gsz;
            by = r2 >> 2;
            bx = xg * 4 + (r2 & 3);
        }
    }
    const int z = bz;
    const int t = threadIdx.x;
    const int n0 = bx * 128;
    const int r0 = by * 128;

    // row-major [128][64] f16, 16 KiB each
    __shared__ alignas(16) unsigned short sA[8192];
    __shared__ alignas(16) unsigned short sB[8192];

    // staging assignment: pass p (0..3) covers rows p*32 + (t>>3); lane chunk t&7.
    const int rsub = t >> 3;              // 0..31
    const int cl = t & 7;                 // LDS 16B-chunk this thread fills
    const int gch = cl ^ (rsub & 7);      // pre-swizzled GLOBAL chunk (row&7 == rsub&7)
    const unsigned short* aP[4];
    const unsigned short* bP[4];
#pragma unroll
    for (int p = 0; p < 4; ++p) {
        int ar = r0 + p * 32 + rsub;
        if (GATHER) {
            const int* rm = rowmap + (size_t)z * rowmap_es;
            if (ar >= Mvalid) ar = Mvalid - 1;
            aP[p] = A + (long long)rm[ar] * K;
        } else {
            aP[p] = A + (long long)z * A_es + (long long)ar * K;
        }
        bP[p] = Bt + (long long)z * Bt_es + (long long)(n0 + p * 32 + rsub) * K;
    }

    const int lane = t & 63;
    const int w = t >> 6;
    const int wy = w >> 1, wx = w & 1;
    const int lm = lane & 15, lq = lane >> 4;
    const int xr = lm & 7;                // read-side XOR (row&7 == lm&7)

    float4v acc[4][4];
#pragma unroll
    for (int a = 0; a < 4; ++a)
#pragma unroll
        for (int b = 0; b < 4; ++b) acc[a][b] = (float4v){0.f, 0.f, 0.f, 0.f};

    const int KB = K >> 6;
    for (int kb = 0; kb < KB; ++kb) {
        const int kOff = kb << 6;         // in f16 elements
#pragma unroll
        for (int p = 0; p < 4; ++p) {
            // global: row segment [kOff .. kOff+64) f16, chunk gch (16 B) of it.
            // per wave-instruction: 8 rows x full 128 B contiguous (coalesced).
            gl2lds16(aP[p] + kOff + gch * 8, &sA[p * 2048 + t * 8]);
            gl2lds16(bP[p] + kOff + gch * 8, &sB[p * 2048 + t * 8]);
        }
        __syncthreads();
#pragma unroll
        for (int ks = 0; ks < 2; ++ks) {
            const int c8k = ks * 4 + lq;  // k-chunk 0..7
            half8 af[4], bf[4];
#pragma unroll
            for (int mi = 0; mi < 4; ++mi) {
                int m = wy * 64 + mi * 16 + lm;
                af[mi] = *(const half8*)&sA[m * 64 + ((c8k ^ xr) << 3)];
            }
#pragma unroll
            for (int ni = 0; ni < 4; ++ni) {
                int nn = wx * 64 + ni * 16 + lm;
                bf[ni] = *(const half8*)&sB[nn * 64 + ((c8k ^ xr) << 3)];
            }
#pragma unroll
            for (int mi = 0; mi < 4; ++mi)
#pragma unroll
                for (int ni = 0; ni < 4; ++ni)
                    acc[mi][ni] = __builtin_amdgcn_mfma_f32_16x16x32_f16(
                        af[mi], bf[ni], acc[mi][ni], 0, 0, 0);
        }
        __syncthreads();
    }

    // epilogue. D mapping: col = lane&15, row = (lane>>4)*4 + reg  [m89-verified]
    const float* biasE = bias + (long long)z * bias_es;
    if (ATOMIC_OUT) {
        float* O = (float*)Out;   // global out [NTOK][N], shared across z
        const int* rm = rowmap + (size_t)z * rowmap_es;
        const float* gE = gate + (size_t)z * gate_es;
#pragma unroll
        for (int mi = 0; mi < 4; ++mi) {
#pragma unroll
            for (int reg = 0; reg < 4; ++reg) {
                int gr = r0 + wy * 64 + mi * 16 + lq * 4 + reg;
                if (gr >= Mvalid) continue;
                int tok = rm[gr];
                float g = gE[gr];
#pragma unroll
                for (int ni = 0; ni < 4; ++ni) {
                    int gc = n0 + wx * 64 + ni * 16 + lm;
                    float v = (acc[mi][ni][reg] + biasE[gc]) * g;
                    atomicAdd(&O[(long long)tok * N + gc], v);
                }
            }
        }
    } else {
        unsigned short* O = (unsigned short*)Out + (long long)z * Out_es;
#pragma unroll
        for (int mi = 0; mi < 4; ++mi) {
#pragma unroll
            for (int reg = 0; reg < 4; ++reg) {
                int gr = r0 + wy * 64 + mi * 16 + lq * 4 + reg;
#pragma unroll
                for (int ni = 0; ni < 4; ++ni) {
                    int gc = n0 + wx * 64 + ni * 16 + lm;
                    float v = acc[mi][ni][reg] + biasE[gc];
                    if (SILU_F16) v = v / (1.f + __expf(-v));
                    O[(long long)gr * N + gc] = f2h_bits(v);
                }
            }
        }
    }
}

// ---------------- host launcher ----------------
extern "C" void kernel_launch(void* const* d_in, const int* in_sizes, int n_in,
                              void* d_out, int out_size, void* d_ws, size_t ws_size,
                              hipStream_t stream)
{
    if (n_in < 7) return;
    const float* x  = (const float*)d_in[0];
    const float* Wr = (const float*)d_in[1];
    const float* br = (const float*)d_in[2];
    const float* W1 = (const float*)d_in[3];
    const float* b1 = (const float*)d_in[4];
    const float* W2 = (const float*)d_in[5];
    const float* b2 = (const float*)d_in[6];
    float* out = (float*)d_out;
    char* ws = (char*)d_ws;

    // out must start at 0: stage-2 accumulates into it atomically.
    hipMemsetAsync(out, 0, (size_t)out_size * sizeof(float), stream);

    size_t off = 0;
    auto take = [&](size_t sz) { size_t o = off; off += (sz + 255) & ~(size_t)255; return o; };
    const size_t o_aexp  = take(4ull * MASS);
    const size_t o_agate = take(4ull * MASS);
    const size_t o_cnt   = take(256);
    const size_t o_bg    = take(4ull * NE * NBUCKET);
    const size_t o_bm    = take(4ull * NE * NBUCKET);
    const size_t o_dtok  = take(4ull * NE * CAP);
    const size_t o_dg    = take(4ull * NE * CAP);
    const size_t o_xf    = take(2ull * NTOK * DMODEL);
    const size_t misc_end = off;

    // tiers: (fullW,fullH) -> (fullW,slimH) -> (slimW,slimH)
    bool fullW = true, fullH = true;
    size_t o_w1t = 0, o_w2t = 0, o_h = 0;
    bool fits = false;
    for (int attempt = 0; attempt < 3; ++attempt) {
        off = misc_end;
        o_w1t = take((fullW ? (size_t)NE : 1) * 2ull * DMODEL * HID);
        o_w2t = take((fullW ? (size_t)NE : 1) * 2ull * DMODEL * HID);
        o_h   = take((fullH ? (size_t)NE : 1) * 2ull * CAPP * HID);
        if (off <= ws_size) { fits = true; break; }
        if (fullH) fullH = false; else fullW = false;
    }
    if (!fits) return;  // out stays zero -> wrong-answer diagnostic, no OOB crash

    int*   aexp   = (int*)(ws + o_aexp);
    float* agate  = (float*)(ws + o_agate);
    int*   cnt    = (int*)(ws + o_cnt);
    float* bg     = (float*)(ws + o_bg);
    int*   bm     = (int*)(ws + o_bm);
    int*   dtok   = (int*)(ws + o_dtok);
    float* dg     = (float*)(ws + o_dg);
    unsigned short* xf  = (unsigned short*)(ws + o_xf);
    unsigned short* W1T = (unsigned short*)(ws + o_w1t);
    unsigned short* W2T = (unsigned short*)(ws + o_w2t);
    unsigned short* hbuf = (unsigned short*)(ws + o_h);

    hipMemsetAsync(cnt, 0, 256, stream);
    hipMemsetAsync(dtok, 0, 4ull * NE * CAP, stream);   // padded slots -> token 0
    hipMemsetAsync(dg, 0, 4ull * NE * CAP, stream);     // padded slots -> gate 0

    router_kernel<<<NTOK / 4, 256, 0, stream>>>(x, Wr, br, aexp, agate);
    bucket_kernel<<<MASS / 256, 256, 0, stream>>>(aexp, agate, cnt, bg, bm);
    rank_kernel<<<dim3(NBUCKET / 256, NE), 256, 0, stream>>>(cnt, bg, bm, dtok, dg);
    cvt_kernel<<<(NTOK * DMODEL) / (256 * 8), 256, 0, stream>>>(x, xf);

    const long long WS = (long long)DMODEL * HID;
    if (fullW) {
        transpose_kernel<<<dim3(HID / 64, DMODEL / 64, NE), 256, 0, stream>>>(W1, WS, W1T, WS, DMODEL, HID);
        transpose_kernel<<<dim3(DMODEL / 64, HID / 64, NE), 256, 0, stream>>>(W2, WS, W2T, WS, HID, DMODEL);
    }

    if (fullH) {
        gemm_bt<true, true, false><<<dim3(HID / 128, CAPP / 128, NE), 256, 0, stream>>>(
            xf, 0, W1T, WS, hbuf, (long long)CAPP * HID,
            b1, HID, dtok, CAP, (const float*)nullptr, 0, DMODEL, HID, CAP);
        gemm_bt<false, false, true><<<dim3(DMODEL / 128, CAPP / 128, NE), 256, 0, stream>>>(
            hbuf, (long long)CAPP * HID, W2T, WS, out, 0,
            b2, DMODEL, dtok, CAP, dg, CAP, HID, DMODEL, CAP);
    } else {
        for (int e = 0; e < NE; ++e) {
            const unsigned short* w1te;
            const unsigned short* w2te;
            if (fullW) {
                w1te = W1T + (size_t)e * WS;
                w2te = W2T + (size_t)e * WS;
            } else {
                transpose_kernel<<<dim3(HID / 64, DMODEL / 64, 1), 256, 0, stream>>>(
                    W1 + (size_t)e * WS, 0, W1T, 0, DMODEL, HID);
                w1te = W1T; w2te = W2T;
            }
            gemm_bt<true, true, false><<<dim3(HID / 128, CAPP / 128, 1), 256, 0, stream>>>(
                xf, 0, w1te, 0, hbuf, 0,
                b1 + (size_t)e * HID, 0, dtok + (size_t)e * CAP, 0,
                (const float*)nullptr, 0, DMODEL, HID, CAP);
            if (!fullW)
                transpose_kernel<<<dim3(DMODEL / 64, HID / 64, 1), 256, 0, stream>>>(
                    W2 + (size_t)e * WS, 0, W2T, 0, HID, DMODEL);
            gemm_bt<false, false, true><<<dim3(DMODEL / 128, CAPP / 128, 1), 256, 0, stream>>>(
                hbuf, 0, w2te, 0, out, 0,
                b2 + (size_t)e * DMODEL, 0, dtok + (size_t)e * CAP, 0,
                dg + (size_t)e * CAP, 0, HID, DMODEL, CAP);
        }
    }
}